// Round 1
// baseline (681.811 us; speedup 1.0000x reference)
//
#include <hip/hip_runtime.h>

#define NPTS   8192
#define KNN    16
#define BALL2f 0.2f
#define FLTMAX 3.402823466e+38f

// 3x3 symmetric eigen -> cond number s0/(s0+s2), analytic (double precision).
__device__ __forceinline__ double cond3(double xx, double xy, double xz,
                                        double yy, double yz, double zz) {
    double q  = (xx + yy + zz) * (1.0 / 3.0);
    double a  = xx - q, b = yy - q, c = zz - q;
    double p1 = xy * xy + xz * xz + yz * yz;
    double p2 = a * a + b * b + c * c + 2.0 * p1;
    if (p2 <= 0.0) return 0.5;              // all eigenvalues equal
    double p   = sqrt(p2 * (1.0 / 6.0));
    double inv = 1.0 / p;
    double b00 = a * inv, b11 = b * inv, b22 = c * inv;
    double b01 = xy * inv, b02 = xz * inv, b12 = yz * inv;
    double detB = b00 * (b11 * b22 - b12 * b12)
                - b01 * (b01 * b22 - b12 * b02)
                + b02 * (b01 * b12 - b11 * b02);
    double r = 0.5 * detB;
    r = fmin(1.0, fmax(-1.0, r));
    double phi = acos(r) * (1.0 / 3.0);
    double l0 = q + 2.0 * p * cos(phi);
    double l2 = q + 2.0 * p * cos(phi + 2.0943951023931953); // +2pi/3
    double s0 = sqrt(fmax(l0, 0.0));
    double s2 = sqrt(fmax(l2, 0.0));
    return s0 / (s0 + s2);
}

__global__ __launch_bounds__(256) void cond_knn_kernel(
        const float* __restrict__ ref, const float* __restrict__ pts,
        double* __restrict__ acc) {
    // LDS: full db (96KB) + merge lists for waves 1..3 (padded to 17)
    __shared__ __align__(16) float sdb[NPTS * 3];
    __shared__ float sld[3][64][17];
    __shared__ int   sli[3][64][17];

    const int tid  = threadIdx.x;
    const int w    = tid >> 6;         // wave 0..3
    const int lane = tid & 63;
    const int b     = blockIdx.x >> 7;           // batch 0..1
    const int qbase = (blockIdx.x & 127) << 6;   // 64 queries per block

    const float* refb = ref + b * NPTS * 3;
    const float* ptsb = pts + b * NPTS * 3;

    // ---- stage full db into LDS (coalesced float4) ----
    {
        const float4* src4 = reinterpret_cast<const float4*>(refb);
        float4* dst4 = reinterpret_cast<float4*>(sdb);
        #pragma unroll
        for (int i = 0; i < (NPTS * 3 / 4) / 256; ++i)
            dst4[tid + i * 256] = src4[tid + i * 256];
    }
    __syncthreads();

    const int qi = qbase + lane;
    const float qx = sdb[3 * qi + 0];
    const float qy = sdb[3 * qi + 1];
    const float qz = sdb[3 * qi + 2];

    // ---- per-wave top-16 over its db quarter ----
    float bd[KNN];
    int   bi[KNN];
    #pragma unroll
    for (int k = 0; k < KNN; ++k) { bd[k] = FLTMAX; bi[k] = 0; }

    auto ins = [&](float dv, int iv) {
        bd[15] = dv; bi[15] = iv;
        #pragma unroll
        for (int kk = 15; kk > 0; --kk) {
            if (bd[kk] < bd[kk - 1]) {
                float td = bd[kk]; bd[kk] = bd[kk - 1]; bd[kk - 1] = td;
                int   ti = bi[kk]; bi[kk] = bi[kk - 1]; bi[kk - 1] = ti;
            }
        }
    };

    const float4* db4 = reinterpret_cast<const float4*>(sdb);
    const int jstart = w * (NPTS / 4);
    const int jend   = jstart + (NPTS / 4);
    for (int j = jstart; j < jend; j += 4) {
        const int i4 = (3 * j) >> 2;
        float4 A = db4[i4 + 0];
        float4 B = db4[i4 + 1];
        float4 C = db4[i4 + 2];
        float dx, dy, dz;
        dx = qx - A.x; dy = qy - A.y; dz = qz - A.z;
        float d0 = dx * dx + dy * dy + dz * dz;
        dx = qx - A.w; dy = qy - B.x; dz = qz - B.y;
        float d1 = dx * dx + dy * dy + dz * dz;
        dx = qx - B.z; dy = qy - B.w; dz = qz - C.x;
        float d2 = dx * dx + dy * dy + dz * dz;
        dx = qx - C.y; dy = qy - C.z; dz = qz - C.w;
        float d3 = dx * dx + dy * dy + dz * dz;
        float dm = fminf(fminf(d0, d1), fminf(d2, d3));
        if (dm < bd[15]) {
            if (d0 < bd[15]) ins(d0, j + 0);
            if (d1 < bd[15]) ins(d1, j + 1);
            if (d2 < bd[15]) ins(d2, j + 2);
            if (d3 < bd[15]) ins(d3, j + 3);
        }
    }

    // ---- waves 1..3 publish lists; wave 0 merges ----
    if (w > 0) {
        #pragma unroll
        for (int k = 0; k < KNN; ++k) {
            sld[w - 1][lane][k] = bd[k];
            sli[w - 1][lane][k] = bi[k];
        }
    }
    __syncthreads();
    if (w != 0) return;

    #pragma unroll
    for (int w2 = 0; w2 < 3; ++w2) {
        #pragma unroll
        for (int k = 0; k < KNN; ++k) {
            float dv = sld[w2][lane][k];
            int   iv = sli[w2][lane][k];
            if (dv < bd[15]) ins(dv, iv);
        }
    }

    // ---- gather + mask + centers ----
    float rx[KNN], ry[KNN], rz[KNN], px[KNN], py[KNN], pz[KNN];
    int mbits = 0;
    float sRx = 0.f, sRy = 0.f, sRz = 0.f, sPx = 0.f, sPy = 0.f, sPz = 0.f;
    #pragma unroll
    for (int k = 0; k < KNN; ++k) {
        int i = bi[k];
        rx[k] = sdb[3 * i + 0]; ry[k] = sdb[3 * i + 1]; rz[k] = sdb[3 * i + 2];
        px[k] = ptsb[3 * i + 0]; py[k] = ptsb[3 * i + 1]; pz[k] = ptsb[3 * i + 2];
        if (bd[k] < BALL2f) {
            mbits |= (1 << k);
            sRx += rx[k]; sRy += ry[k]; sRz += rz[k];
        }
        sPx += px[k]; sPy += py[k]; sPz += pz[k];
    }
    int nb = __popc(mbits);               // >= 1 (self distance is 0)
    double inb = 1.0 / (double)nb;
    double cRx = (double)sRx * inb, cRy = (double)sRy * inb, cRz = (double)sRz * inb;
    double cPx = (double)sPx * inb, cPy = (double)sPy * inb, cPz = (double)sPz * inb;

    // ---- Gram matrices (double) ----
    double Rxx = 0, Rxy = 0, Rxz = 0, Ryy = 0, Ryz = 0, Rzz = 0;
    double Pxx = 0, Pxy = 0, Pxz = 0, Pyy = 0, Pyz = 0, Pzz = 0;
    #pragma unroll
    for (int k = 0; k < KNN; ++k) {
        bool m = (mbits >> k) & 1;
        double ax = (m ? (double)rx[k] : 0.0) - cRx;
        double ay = (m ? (double)ry[k] : 0.0) - cRy;
        double az = (m ? (double)rz[k] : 0.0) - cRz;
        Rxx += ax * ax; Rxy += ax * ay; Rxz += ax * az;
        Ryy += ay * ay; Ryz += ay * az; Rzz += az * az;
        double bx = (double)px[k] - cPx;
        double by = (double)py[k] - cPy;
        double bz = (double)pz[k] - cPz;
        Pxx += bx * bx; Pxy += bx * by; Pxz += bx * bz;
        Pyy += by * by; Pyz += by * bz; Pzz += bz * bz;
    }
    double condR = cond3(Rxx, Rxy, Rxz, Ryy, Ryz, Rzz);
    double condP = cond3(Pxx, Pxy, Pxz, Pyy, Pyz, Pzz);
    double t = condP - condR;
    t = t * t;

    // ---- wave reduce + one atomic per block ----
    #pragma unroll
    for (int off = 32; off > 0; off >>= 1) t += __shfl_down(t, off);
    if (lane == 0) atomicAdd(acc, t);
}

__global__ void finalize_kernel(const double* __restrict__ acc,
                                float* __restrict__ out) {
    out[0] = (float)(acc[0] * (1.0 / 16384.0));
}

extern "C" void kernel_launch(void* const* d_in, const int* in_sizes, int n_in,
                              void* d_out, int out_size, void* d_ws, size_t ws_size,
                              hipStream_t stream) {
    const float* ref = (const float*)d_in[0];
    const float* pts = (const float*)d_in[1];
    float* out = (float*)d_out;
    double* acc = (double*)d_ws;

    hipMemsetAsync(acc, 0, sizeof(double), stream);
    hipLaunchKernelGGL(cond_knn_kernel, dim3(256), dim3(256), 0, stream,
                       ref, pts, acc);
    hipLaunchKernelGGL(finalize_kernel, dim3(1), dim3(1), 0, stream, acc, out);
}

// Round 2
// 160.407 us; speedup vs baseline: 4.2505x; 4.2505x over previous
//
#include <hip/hip_runtime.h>

#define NPTS   8192
#define KNN    16
#define BALL2f 0.2f
#define FLTMAX 3.402823466e+38f
#define G      8
#define NCELLS 512           // G^3
#define CELLSZ 0.125f

// ---- ws layout (bytes) ----
// 0      : double acc
// 16     : int counts[2][512]          (zeroed)
// 4112   : int cursor[2][512]          (zeroed)
// 8208   : int starts[2][513]
// 12320  : float4 rsort[2][8192]       (262144 B)
// 274464 : float4 psort[2][8192]       (262144 B)
#define WS_ACC    0
#define WS_COUNTS 16
#define WS_CURSOR 4112
#define WS_STARTS 8208
#define WS_RSORT  12320
#define WS_PSORT  274464
#define WS_ZERO_BYTES 8208

__device__ __forceinline__ int cell_of(float x, float y, float z) {
    int cx = (int)(x * (float)G); cx = cx < 0 ? 0 : (cx > G - 1 ? G - 1 : cx);
    int cy = (int)(y * (float)G); cy = cy < 0 ? 0 : (cy > G - 1 ? G - 1 : cy);
    int cz = (int)(z * (float)G); cz = cz < 0 ? 0 : (cz > G - 1 ? G - 1 : cz);
    return (cz * G + cy) * G + cx;
}

__global__ __launch_bounds__(256) void count_kernel(
        const float* __restrict__ ref, int* __restrict__ counts) {
    int t = blockIdx.x * 256 + threadIdx.x;
    if (t >= 2 * NPTS) return;
    int b = t >> 13, i = t & (NPTS - 1);
    const float* p = ref + (size_t)(b * NPTS + i) * 3;
    atomicAdd(&counts[b * NCELLS + cell_of(p[0], p[1], p[2])], 1);
}

__global__ __launch_bounds__(512) void scan_kernel(
        const int* __restrict__ counts, int* __restrict__ starts) {
    __shared__ int s[NCELLS];
    int b = blockIdx.x, t = threadIdx.x;
    int v = counts[b * NCELLS + t];
    s[t] = v;
    __syncthreads();
    for (int off = 1; off < NCELLS; off <<= 1) {
        int x = (t >= off) ? s[t - off] : 0;
        __syncthreads();
        s[t] += x;
        __syncthreads();
    }
    starts[b * (NCELLS + 1) + t] = s[t] - v;      // exclusive
    if (t == NCELLS - 1) starts[b * (NCELLS + 1) + NCELLS] = s[t];
}

__global__ __launch_bounds__(256) void scatter_kernel(
        const float* __restrict__ ref, const float* __restrict__ pts,
        const int* __restrict__ starts, int* __restrict__ cursor,
        float4* __restrict__ rs, float4* __restrict__ ps) {
    int t = blockIdx.x * 256 + threadIdx.x;
    if (t >= 2 * NPTS) return;
    int b = t >> 13, i = t & (NPTS - 1);
    const float* r = ref + (size_t)(b * NPTS + i) * 3;
    const float* p = pts + (size_t)(b * NPTS + i) * 3;
    float x = r[0], y = r[1], z = r[2];
    int cell = cell_of(x, y, z);
    int pos = starts[b * (NCELLS + 1) + cell] + atomicAdd(&cursor[b * NCELLS + cell], 1);
    rs[b * NPTS + pos] = make_float4(x, y, z, 0.f);
    ps[b * NPTS + pos] = make_float4(p[0], p[1], p[2], 0.f);
}

// 3x3 symmetric eigen -> cond number s0/(s0+s2), analytic (double precision).
__device__ __forceinline__ double cond3(double xx, double xy, double xz,
                                        double yy, double yz, double zz) {
    double q  = (xx + yy + zz) * (1.0 / 3.0);
    double a  = xx - q, b = yy - q, c = zz - q;
    double p1 = xy * xy + xz * xz + yz * yz;
    double p2 = a * a + b * b + c * c + 2.0 * p1;
    if (p2 <= 0.0) return 0.5;
    double p   = sqrt(p2 * (1.0 / 6.0));
    double inv = 1.0 / p;
    double b00 = a * inv, b11 = b * inv, b22 = c * inv;
    double b01 = xy * inv, b02 = xz * inv, b12 = yz * inv;
    double detB = b00 * (b11 * b22 - b12 * b12)
                - b01 * (b01 * b22 - b12 * b02)
                + b02 * (b01 * b12 - b11 * b02);
    double r = 0.5 * detB;
    r = fmin(1.0, fmax(-1.0, r));
    double phi = acos(r) * (1.0 / 3.0);
    double l0 = q + 2.0 * p * cos(phi);
    double l2 = q + 2.0 * p * cos(phi + 2.0943951023931953);
    double s0 = sqrt(fmax(l0, 0.0));
    double s2 = sqrt(fmax(l2, 0.0));
    return s0 / (s0 + s2);
}

__global__ __launch_bounds__(512) void cond_knn_kernel(
        const float4* __restrict__ rs, const float4* __restrict__ ps,
        const int* __restrict__ starts, double* __restrict__ acc) {
    __shared__ float sld[4][64][17];
    __shared__ int   sli[4][64][17];
    __shared__ float d16s[64];
    __shared__ unsigned char doneA[64];
    __shared__ int flagS;

    const int tid  = threadIdx.x;
    const int w    = tid >> 6;
    const int lane = tid & 63;
    const int b     = blockIdx.x >> 7;
    const int qbase = (blockIdx.x & 127) << 6;

    const float4* rs4 = rs + (size_t)b * NPTS;
    const float4* ps4 = ps + (size_t)b * NPTS;
    const int* st = starts + b * (NCELLS + 1);

    float4 Q = rs4[qbase + lane];
    const float qx = Q.x, qy = Q.y, qz = Q.z;
    int cx = (int)(qx * (float)G); cx = cx < 0 ? 0 : (cx > G - 1 ? G - 1 : cx);
    int cy = (int)(qy * (float)G); cy = cy < 0 ? 0 : (cy > G - 1 ? G - 1 : cy);
    int cz = (int)(qz * (float)G); cz = cz < 0 ? 0 : (cz > G - 1 ? G - 1 : cz);

    float bd[KNN];
    int   bi[KNN];
    #pragma unroll
    for (int k = 0; k < KNN; ++k) { bd[k] = FLTMAX; bi[k] = 0; }

    auto ins = [&](float dv, int iv) {
        bd[15] = dv; bi[15] = iv;
        #pragma unroll
        for (int kk = 15; kk > 0; --kk) {
            if (bd[kk] < bd[kk - 1]) {
                float td = bd[kk]; bd[kk] = bd[kk - 1]; bd[kk - 1] = td;
                int   ti = bi[kk]; bi[kk] = bi[kk - 1]; bi[kk - 1] = ti;
            }
        }
    };

    auto scanCell = [&](int cell, float cut) {
        int s0 = st[cell], s1 = st[cell + 1];
        for (int t2 = s0; t2 < s1; ++t2) {
            float4 P = rs4[t2];
            float dx = qx - P.x, dy = qy - P.y, dz = qz - P.z;
            float d = dx * dx + dy * dy + dz * dz;
            if (d < cut && d < bd[15]) ins(d, t2);
        }
    };

    auto mergeToW0 = [&]() {
        #pragma unroll
        for (int rnd = 0; rnd < 3; ++rnd) {
            int s = 1 << rnd;
            int slot = w >> (rnd + 1);
            bool pub = ((w & (2 * s - 1)) == s);
            bool mrg = ((w & (2 * s - 1)) == 0);
            __syncthreads();
            if (pub) {
                #pragma unroll
                for (int k = 0; k < KNN; ++k) {
                    sld[slot][lane][k] = bd[k];
                    sli[slot][lane][k] = bi[k];
                }
            }
            __syncthreads();
            if (mrg) {
                #pragma unroll
                for (int k = 0; k < KNN; ++k) {
                    float dv = sld[slot][lane][k];
                    if (dv < bd[15]) ins(dv, sli[slot][lane][k]);
                }
            }
        }
    };

    // ---- shells 0+1: the 27-cell box, split across 8 waves ----
    {
        int counter = 0;
        #pragma unroll
        for (int dz = -1; dz <= 1; ++dz)
        #pragma unroll
        for (int dy = -1; dy <= 1; ++dy)
        #pragma unroll
        for (int dx = -1; dx <= 1; ++dx) {
            int cc = counter++;
            if ((cc & 7) != w) continue;
            int nx = cx + dx, ny = cy + dy, nz = cz + dz;
            if ((unsigned)nx > (unsigned)(G - 1) || (unsigned)ny > (unsigned)(G - 1) ||
                (unsigned)nz > (unsigned)(G - 1)) continue;
            scanCell((nz * G + ny) * G + nx, FLTMAX);
        }
    }
    mergeToW0();

    // ---- expanding shells until merged d16 certified ----
    int r_done = 1;
    while (true) {
        if (tid == 0) flagS = 0;
        __syncthreads();
        if (w == 0) {
            float bound = (float)r_done * CELLSZ;
            bool dn = bd[15] <= bound * bound;
            d16s[lane] = bd[15];
            doneA[lane] = dn ? 1 : 0;
            if (__any(!dn) && lane == 0) flagS = 1;
        }
        __syncthreads();
        if (!flagS || r_done >= G) break;
        int r = r_done + 1;
        if (w != 0) {
            #pragma unroll
            for (int k = 0; k < KNN; ++k) { bd[k] = FLTMAX; bi[k] = 0; }
        }
        float cut = d16s[lane];
        bool active = !doneA[lane];
        int counter = 0;
        for (int dz = -r; dz <= r; ++dz)
        for (int dy = -r; dy <= r; ++dy)
        for (int dx = -r; dx <= r; ++dx) {
            int adx = dx < 0 ? -dx : dx, ady = dy < 0 ? -dy : dy, adz = dz < 0 ? -dz : dz;
            int m = adx > ady ? adx : ady; m = m > adz ? m : adz;
            if (m != r) continue;                 // shell only (uniform)
            int cc = counter++;
            if ((cc & 7) != w) continue;
            if (!active) continue;
            int nx = cx + dx, ny = cy + dy, nz = cz + dz;
            if ((unsigned)nx > (unsigned)(G - 1) || (unsigned)ny > (unsigned)(G - 1) ||
                (unsigned)nz > (unsigned)(G - 1)) continue;
            scanCell((nz * G + ny) * G + nx, cut);
        }
        mergeToW0();
        r_done = r;
    }

    if (w != 0) return;

    // ---- gather + mask + centers (wave 0 only; lane = query) ----
    float rx[KNN], ry[KNN], rz[KNN], px[KNN], py[KNN], pz[KNN];
    int mbits = 0;
    float sRx = 0.f, sRy = 0.f, sRz = 0.f, sPx = 0.f, sPy = 0.f, sPz = 0.f;
    #pragma unroll
    for (int k = 0; k < KNN; ++k) {
        int i = bi[k];
        float4 R = rs4[i];
        float4 P = ps4[i];
        rx[k] = R.x; ry[k] = R.y; rz[k] = R.z;
        px[k] = P.x; py[k] = P.y; pz[k] = P.z;
        if (bd[k] < BALL2f) {
            mbits |= (1 << k);
            sRx += rx[k]; sRy += ry[k]; sRz += rz[k];
        }
        sPx += px[k]; sPy += py[k]; sPz += pz[k];
    }
    int nb = __popc(mbits);
    double inb = 1.0 / (double)nb;
    double cRx = (double)sRx * inb, cRy = (double)sRy * inb, cRz = (double)sRz * inb;
    double cPx = (double)sPx * inb, cPy = (double)sPy * inb, cPz = (double)sPz * inb;

    double Rxx = 0, Rxy = 0, Rxz = 0, Ryy = 0, Ryz = 0, Rzz = 0;
    double Pxx = 0, Pxy = 0, Pxz = 0, Pyy = 0, Pyz = 0, Pzz = 0;
    #pragma unroll
    for (int k = 0; k < KNN; ++k) {
        bool m = (mbits >> k) & 1;
        double ax = (m ? (double)rx[k] : 0.0) - cRx;
        double ay = (m ? (double)ry[k] : 0.0) - cRy;
        double az = (m ? (double)rz[k] : 0.0) - cRz;
        Rxx += ax * ax; Rxy += ax * ay; Rxz += ax * az;
        Ryy += ay * ay; Ryz += ay * az; Rzz += az * az;
        double bx = (double)px[k] - cPx;
        double by = (double)py[k] - cPy;
        double bz = (double)pz[k] - cPz;
        Pxx += bx * bx; Pxy += bx * by; Pxz += bx * bz;
        Pyy += by * by; Pyz += by * bz; Pzz += bz * bz;
    }
    double condR = cond3(Rxx, Rxy, Rxz, Ryy, Ryz, Rzz);
    double condP = cond3(Pxx, Pxy, Pxz, Pyy, Pyz, Pzz);
    double t = condP - condR;
    t = t * t;

    #pragma unroll
    for (int off = 32; off > 0; off >>= 1) t += __shfl_down(t, off);
    if (lane == 0) atomicAdd(acc, t);
}

__global__ void finalize_kernel(const double* __restrict__ acc,
                                float* __restrict__ out) {
    out[0] = (float)(acc[0] * (1.0 / 16384.0));
}

extern "C" void kernel_launch(void* const* d_in, const int* in_sizes, int n_in,
                              void* d_out, int out_size, void* d_ws, size_t ws_size,
                              hipStream_t stream) {
    const float* ref = (const float*)d_in[0];
    const float* pts = (const float*)d_in[1];
    char* ws = (char*)d_ws;
    double* acc   = (double*)(ws + WS_ACC);
    int* counts   = (int*)(ws + WS_COUNTS);
    int* cursor   = (int*)(ws + WS_CURSOR);
    int* starts   = (int*)(ws + WS_STARTS);
    float4* rsort = (float4*)(ws + WS_RSORT);
    float4* psort = (float4*)(ws + WS_PSORT);

    hipMemsetAsync(ws, 0, WS_ZERO_BYTES, stream);
    hipLaunchKernelGGL(count_kernel,   dim3(64),  dim3(256), 0, stream, ref, counts);
    hipLaunchKernelGGL(scan_kernel,    dim3(2),   dim3(512), 0, stream, counts, starts);
    hipLaunchKernelGGL(scatter_kernel, dim3(64),  dim3(256), 0, stream, ref, pts, starts, cursor, rsort, psort);
    hipLaunchKernelGGL(cond_knn_kernel, dim3(256), dim3(512), 0, stream, rsort, psort, starts, acc);
    hipLaunchKernelGGL(finalize_kernel, dim3(1),  dim3(1),   0, stream, acc, (float*)d_out);
}

// Round 3
// 125.143 us; speedup vs baseline: 5.4483x; 1.2818x over previous
//
#include <hip/hip_runtime.h>

#define NPTS   8192
#define KNN    16
#define G      10
#define NCELLS 1000          // G^3
#define CELLSZ 0.1f
#define BALL2f 0.2f
#define TRUNCM 0xFFFFE000u   // keep top 19 bits of f32(d^2)
#define IDXM   0x1FFFu       // low 13 bits = point index (< 8192)

// ---- ws layout (bytes) ----
#define WS_ACC    0          // double acc
#define WS_STARTS 16         // int gstarts[2][1001]
#define WS_RSORT  8032       // float4 rsort[2][8192]
#define WS_PSORT  270176     // float4 psort[2][8192]

__device__ __forceinline__ int clampg(int v) { return v < 0 ? 0 : (v > G - 1 ? G - 1 : v); }

// ---- fused binning: count -> scan -> scatter (one block per batch) ----
__global__ __launch_bounds__(1024) void prep_kernel(
        const float* __restrict__ ref, const float* __restrict__ pts,
        int* __restrict__ gstarts, float4* __restrict__ rs, float4* __restrict__ ps,
        double* __restrict__ acc) {
    __shared__ int cnt[NCELLS];
    __shared__ int st[NCELLS + 1];
    __shared__ int cur[NCELLS];
    const int b = blockIdx.x, t = threadIdx.x;
    if (b == 0 && t == 0) acc[0] = 0.0;
    for (int i = t; i < NCELLS; i += 1024) { cnt[i] = 0; cur[i] = 0; }
    __syncthreads();
    const float* rb = ref + (size_t)b * NPTS * 3;
    const float* pb = pts + (size_t)b * NPTS * 3;
    int cellv[8];
    #pragma unroll
    for (int k = 0; k < 8; ++k) {
        int i = t + k * 1024;
        float x = rb[3 * i], y = rb[3 * i + 1], z = rb[3 * i + 2];
        int c = (clampg((int)(z * (float)G)) * G + clampg((int)(y * (float)G))) * G
              + clampg((int)(x * (float)G));
        cellv[k] = c;
        atomicAdd(&cnt[c], 1);
    }
    __syncthreads();
    // Hillis-Steele inclusive scan over NCELLS
    for (int off = 1; off < NCELLS; off <<= 1) {
        int x = 0;
        if (t < NCELLS && t >= off) x = cnt[t - off];
        __syncthreads();
        if (t < NCELLS) cnt[t] += x;
        __syncthreads();
    }
    if (t < NCELLS) st[t + 1] = cnt[t];
    if (t == 0) st[0] = 0;
    __syncthreads();
    if (t <= NCELLS) gstarts[b * (NCELLS + 1) + t] = st[t];
    #pragma unroll
    for (int k = 0; k < 8; ++k) {
        int i = t + k * 1024;
        int c = cellv[k];
        int pos = st[c] + atomicAdd(&cur[c], 1);
        float x = rb[3 * i], y = rb[3 * i + 1], z = rb[3 * i + 2];
        rs[(size_t)b * NPTS + pos] = make_float4(x, y, z, 0.f);
        ps[(size_t)b * NPTS + pos] = make_float4(pb[3 * i], pb[3 * i + 1], pb[3 * i + 2], 0.f);
    }
}

// 3x3 symmetric eigen -> cond number s0/(s0+s2), analytic (double precision).
__device__ __forceinline__ double cond3(double xx, double xy, double xz,
                                        double yy, double yz, double zz) {
    double q  = (xx + yy + zz) * (1.0 / 3.0);
    double a  = xx - q, b = yy - q, c = zz - q;
    double p1 = xy * xy + xz * xz + yz * yz;
    double p2 = a * a + b * b + c * c + 2.0 * p1;
    if (p2 <= 0.0) return 0.5;
    double p   = sqrt(p2 * (1.0 / 6.0));
    double inv = 1.0 / p;
    double b00 = a * inv, b11 = b * inv, b22 = c * inv;
    double b01 = xy * inv, b02 = xz * inv, b12 = yz * inv;
    double detB = b00 * (b11 * b22 - b12 * b12)
                - b01 * (b01 * b22 - b12 * b02)
                + b02 * (b01 * b12 - b11 * b02);
    double r = 0.5 * detB;
    r = fmin(1.0, fmax(-1.0, r));
    double phi = acos(r) * (1.0 / 3.0);
    double l0 = q + 2.0 * p * cos(phi);
    double l2 = q + 2.0 * p * cos(phi + 2.0943951023931953);
    double s0 = sqrt(fmax(l0, 0.0));
    double s2 = sqrt(fmax(l2, 0.0));
    return s0 / (s0 + s2);
}

__global__ __launch_bounds__(1024) void cond_knn_kernel(
        const float4* __restrict__ rs, const float4* __restrict__ ps,
        const int* __restrict__ gstarts, double* __restrict__ acc) {
    __shared__ unsigned sld[8][64][17];    // merge slots (packed keys), pad 17
    __shared__ int sst[NCELLS + 1];
    __shared__ unsigned cutp[64];
    __shared__ unsigned char doneA[64];
    __shared__ int flagS;

    const int tid  = threadIdx.x;
    const int w    = tid >> 6;             // wave 0..15
    const int lane = tid & 63;
    const int b     = blockIdx.x >> 7;
    const int qbase = (blockIdx.x & 127) << 6;

    const float4* rs4 = rs + (size_t)b * NPTS;
    const float4* ps4 = ps + (size_t)b * NPTS;

    for (int i = tid; i < NCELLS + 1; i += 1024)
        sst[i] = gstarts[b * (NCELLS + 1) + i];
    __syncthreads();

    float4 Q = rs4[qbase + lane];
    const float qx = Q.x, qy = Q.y, qz = Q.z;
    const int cx = clampg((int)(qx * (float)G));
    const int cy = clampg((int)(qy * (float)G));
    const int cz = clampg((int)(qz * (float)G));

    unsigned bq[KNN];
    #pragma unroll
    for (int k = 0; k < KNN; ++k) bq[k] = 0xFFFFFFFFu;

    auto scanRange = [&](int s0, int s1, unsigned cutv) {
        for (int t2 = s0; t2 < s1; ++t2) {
            float4 P = rs4[t2];
            float dx = qx - P.x, dy = qy - P.y, dz = qz - P.z;
            float d = fmaf(dx, dx, fmaf(dy, dy, dz * dz));
            unsigned v = (__float_as_uint(d) & TRUNCM) | (unsigned)t2;
            unsigned cv = cutv < bq[15] ? cutv : bq[15];
            if (v < cv) {
                bq[15] = v;
                #pragma unroll
                for (int kk = 15; kk >= 1; --kk) {
                    unsigned lo = min(bq[kk - 1], bq[kk]);
                    unsigned hi = max(bq[kk - 1], bq[kk]);
                    bq[kk - 1] = lo; bq[kk] = hi;
                }
            }
        }
    };

    auto mergeToW0 = [&]() {
        #pragma unroll
        for (int rnd = 0; rnd < 4; ++rnd) {
            int s = 1 << rnd;
            int slot = w >> (rnd + 1);
            __syncthreads();
            if ((w & (2 * s - 1)) == s) {
                #pragma unroll
                for (int k = 0; k < KNN; ++k) sld[slot][lane][k] = bq[k];
            }
            __syncthreads();
            if ((w & (2 * s - 1)) == 0) {
                #pragma unroll
                for (int k = 0; k < KNN; ++k) {
                    unsigned v = sld[slot][lane][k];
                    if (v < bq[15]) {
                        bq[15] = v;
                        #pragma unroll
                        for (int kk = 15; kk >= 1; --kk) {
                            unsigned lo = min(bq[kk - 1], bq[kk]);
                            unsigned hi = max(bq[kk - 1], bq[kk]);
                            bq[kk - 1] = lo; bq[kk] = hi;
                        }
                    }
                }
            }
        }
    };

    // ---- initial 27-cell box, 54 half-cell chunks over 16 waves ----
    {
        int counter = 0;
        #pragma unroll
        for (int dz = -1; dz <= 1; ++dz)
        #pragma unroll
        for (int dy = -1; dy <= 1; ++dy)
        #pragma unroll
        for (int dx = -1; dx <= 1; ++dx) {
            #pragma unroll
            for (int h = 0; h < 2; ++h) {
                int cc = counter++;
                if ((cc & 15) != w) continue;
                int nx = cx + dx, ny = cy + dy, nz = cz + dz;
                if ((unsigned)nx > (unsigned)(G - 1) || (unsigned)ny > (unsigned)(G - 1) ||
                    (unsigned)nz > (unsigned)(G - 1)) continue;
                int cell = (nz * G + ny) * G + nx;
                int s0 = sst[cell], s1 = sst[cell + 1];
                int mid = (s0 + s1) >> 1;
                if (h == 0) scanRange(s0, mid, 0xFFFFFFFFu);
                else        scanRange(mid, s1, 0xFFFFFFFFu);
            }
        }
    }
    mergeToW0();

    // ---- expanding shells until certified ----
    int r_done = 1;
    while (true) {
        if (tid == 0) flagS = 0;
        __syncthreads();
        if (w == 0) {
            float bound = (float)r_done * CELLSZ;
            float d16t  = __uint_as_float(bq[15] & TRUNCM);
            bool dn = d16t <= bound * bound * 0.999f;
            cutp[lane]  = bq[15];
            doneA[lane] = dn ? 1 : 0;
            bool anyn = __any(!dn);
            if (anyn && lane == 0) flagS = 1;
        }
        __syncthreads();
        if (!flagS || r_done >= G) break;
        int r = r_done + 1;
        if (w != 0) {
            #pragma unroll
            for (int k = 0; k < KNN; ++k) bq[k] = 0xFFFFFFFFu;
        }
        unsigned cut = cutp[lane];
        bool active = !doneA[lane];
        int counter = 0;
        for (int dz = -r; dz <= r; ++dz)
        for (int dy = -r; dy <= r; ++dy)
        for (int dx = -r; dx <= r; ++dx) {
            int adx = dx < 0 ? -dx : dx, ady = dy < 0 ? -dy : dy, adz = dz < 0 ? -dz : dz;
            int m = adx > ady ? adx : ady; m = m > adz ? m : adz;
            if (m != r) continue;
            int cc = counter++;
            if ((cc & 15) != w) continue;
            if (!active) continue;
            int nx = cx + dx, ny = cy + dy, nz = cz + dz;
            if ((unsigned)nx > (unsigned)(G - 1) || (unsigned)ny > (unsigned)(G - 1) ||
                (unsigned)nz > (unsigned)(G - 1)) continue;
            int cell = (nz * G + ny) * G + nx;
            scanRange(sst[cell], sst[cell + 1], cut);
        }
        mergeToW0();
        r_done = r;
    }

    if (w != 0) return;

    // ---- epilogue: gather + mask + Gram + cond (wave 0; lane = query) ----
    float rx[KNN], ry[KNN], rz[KNN], px[KNN], py[KNN], pz[KNN];
    int mbits = 0;
    float sRx = 0.f, sRy = 0.f, sRz = 0.f, sPx = 0.f, sPy = 0.f, sPz = 0.f;
    #pragma unroll
    for (int k = 0; k < KNN; ++k) {
        int i = (int)(bq[k] & IDXM);
        float du = __uint_as_float(bq[k] & TRUNCM);
        float4 R = rs4[i];
        float4 P = ps4[i];
        rx[k] = R.x; ry[k] = R.y; rz[k] = R.z;
        px[k] = P.x; py[k] = P.y; pz[k] = P.z;
        if (du < BALL2f) {
            mbits |= (1 << k);
            sRx += rx[k]; sRy += ry[k]; sRz += rz[k];
        }
        sPx += px[k]; sPy += py[k]; sPz += pz[k];
    }
    int nb = __popc(mbits);
    double inb = 1.0 / (double)nb;
    double cRx = (double)sRx * inb, cRy = (double)sRy * inb, cRz = (double)sRz * inb;
    double cPx = (double)sPx * inb, cPy = (double)sPy * inb, cPz = (double)sPz * inb;

    double Rxx = 0, Rxy = 0, Rxz = 0, Ryy = 0, Ryz = 0, Rzz = 0;
    double Pxx = 0, Pxy = 0, Pxz = 0, Pyy = 0, Pyz = 0, Pzz = 0;
    #pragma unroll
    for (int k = 0; k < KNN; ++k) {
        bool m = (mbits >> k) & 1;
        double ax = (m ? (double)rx[k] : 0.0) - cRx;
        double ay = (m ? (double)ry[k] : 0.0) - cRy;
        double az = (m ? (double)rz[k] : 0.0) - cRz;
        Rxx += ax * ax; Rxy += ax * ay; Rxz += ax * az;
        Ryy += ay * ay; Ryz += ay * az; Rzz += az * az;
        double bx = (double)px[k] - cPx;
        double by = (double)py[k] - cPy;
        double bz = (double)pz[k] - cPz;
        Pxx += bx * bx; Pxy += bx * by; Pxz += bx * bz;
        Pyy += by * by; Pyz += by * bz; Pzz += bz * bz;
    }
    double condR = cond3(Rxx, Rxy, Rxz, Ryy, Ryz, Rzz);
    double condP = cond3(Pxx, Pxy, Pxz, Pyy, Pyz, Pzz);
    double t = condP - condR;
    t = t * t;

    #pragma unroll
    for (int off = 32; off > 0; off >>= 1) t += __shfl_down(t, off);
    if (lane == 0) atomicAdd(acc, t);
}

__global__ void finalize_kernel(const double* __restrict__ acc,
                                float* __restrict__ out) {
    out[0] = (float)(acc[0] * (1.0 / 16384.0));
}

extern "C" void kernel_launch(void* const* d_in, const int* in_sizes, int n_in,
                              void* d_out, int out_size, void* d_ws, size_t ws_size,
                              hipStream_t stream) {
    const float* ref = (const float*)d_in[0];
    const float* pts = (const float*)d_in[1];
    char* ws = (char*)d_ws;
    double* acc   = (double*)(ws + WS_ACC);
    int* gstarts  = (int*)(ws + WS_STARTS);
    float4* rsort = (float4*)(ws + WS_RSORT);
    float4* psort = (float4*)(ws + WS_PSORT);

    hipLaunchKernelGGL(prep_kernel,     dim3(2),   dim3(1024), 0, stream,
                       ref, pts, gstarts, rsort, psort, acc);
    hipLaunchKernelGGL(cond_knn_kernel, dim3(256), dim3(1024), 0, stream,
                       rsort, psort, gstarts, acc);
    hipLaunchKernelGGL(finalize_kernel, dim3(1),   dim3(1),    0, stream, acc, (float*)d_out);
}

// Round 4
// 105.398 us; speedup vs baseline: 6.4689x; 1.1873x over previous
//
#include <hip/hip_runtime.h>

#define NPTS   8192
#define KNN    16
#define G      10
#define NCELLS 1000          // G^3
#define CAP    32            // bucket capacity (Poisson(8.2) overflow ~1e-11)
#define CELLSZ 0.1f
#define BALL2f 0.2f
#define TRUNCM 0xFFFFE000u   // top 19 bits of f32(d^2)
#define IDXM   0x1FFFu       // low 13 bits = original point index
#define NBLK   256           // knn blocks
#define FLTMAX 3.402823466e+38f

// ---- ws layout (bytes) ----
#define WS_ACC   0           // double acc
#define WS_DONE  8           // int done counter (+pad)
#define WS_CNT   16          // int gcnt[2][1000]
#define WS_RSORT 8224        // float4 buckets[2][1000][32]
#define WS_ZERO  8216

__device__ __forceinline__ int clampg(int v) { return v < 0 ? 0 : (v > G - 1 ? G - 1 : v); }

// ---- fused count+scatter into fixed-capacity buckets ----
__global__ __launch_bounds__(256) void bin_kernel(
        const float* __restrict__ ref, int* __restrict__ gcnt,
        float4* __restrict__ rs) {
    int t = blockIdx.x * 256 + threadIdx.x;
    if (t >= 2 * NPTS) return;
    int b = t >> 13, i = t & (NPTS - 1);
    const float* rb = ref + (size_t)b * NPTS * 3 + 3 * (size_t)i;
    float x = rb[0], y = rb[1], z = rb[2];
    int c = (clampg((int)(z * (float)G)) * G + clampg((int)(y * (float)G))) * G
          + clampg((int)(x * (float)G));
    int slot = atomicAdd(&gcnt[b * NCELLS + c], 1);
    if (slot < CAP)
        rs[(size_t)b * NCELLS * CAP + c * CAP + slot] =
            make_float4(x, y, z, __uint_as_float((unsigned)i));
}

// 3x3 symmetric eigen -> cond number s0/(s0+s2), analytic (double precision).
__device__ __forceinline__ double cond3(double xx, double xy, double xz,
                                        double yy, double yz, double zz) {
    double q  = (xx + yy + zz) * (1.0 / 3.0);
    double a  = xx - q, b = yy - q, c = zz - q;
    double p1 = xy * xy + xz * xz + yz * yz;
    double p2 = a * a + b * b + c * c + 2.0 * p1;
    if (p2 <= 0.0) return 0.5;
    double p   = sqrt(p2 * (1.0 / 6.0));
    double inv = 1.0 / p;
    double b00 = a * inv, b11 = b * inv, b22 = c * inv;
    double b01 = xy * inv, b02 = xz * inv, b12 = yz * inv;
    double detB = b00 * (b11 * b22 - b12 * b12)
                - b01 * (b01 * b22 - b12 * b02)
                + b02 * (b01 * b12 - b11 * b02);
    double r = 0.5 * detB;
    r = fmin(1.0, fmax(-1.0, r));
    double phi = acos(r) * (1.0 / 3.0);
    double l0 = q + 2.0 * p * cos(phi);
    double l2 = q + 2.0 * p * cos(phi + 2.0943951023931953);
    double s0 = sqrt(fmax(l0, 0.0));
    double s2 = sqrt(fmax(l2, 0.0));
    return s0 / (s0 + s2);
}

__global__ __launch_bounds__(1024) void cond_knn_kernel(
        const float* __restrict__ ref, const float* __restrict__ pts,
        const float4* __restrict__ rs, const int* __restrict__ gcnt,
        double* __restrict__ acc, int* __restrict__ done,
        float* __restrict__ out) {
    __shared__ unsigned sld[8][64][17];
    __shared__ int scnt[1024];
    __shared__ int ss[1025];
    __shared__ int wsum[16];
    __shared__ unsigned cutp[64];
    __shared__ unsigned char doneA[64];
    __shared__ int flagS;

    const int tid  = threadIdx.x;
    const int w    = tid >> 6;             // wave 0..15
    const int lane = tid & 63;
    const int b     = blockIdx.x >> 7;
    const int qbase = (blockIdx.x & 127) << 6;
    const float4* rs4 = rs + (size_t)b * NCELLS * CAP;

    // ---- stage counts + block-wide exclusive scan (shuffle-based) ----
    int myc = 0;
    if (tid < NCELLS) { myc = gcnt[b * NCELLS + tid]; myc = myc > CAP ? CAP : myc; }
    scnt[tid] = myc;
    int v = myc;
    #pragma unroll
    for (int off = 1; off < 64; off <<= 1) {
        int u = __shfl_up(v, off, 64);
        if (lane >= off) v += u;
    }
    if (lane == 63) wsum[w] = v;
    __syncthreads();
    if (tid == 0) {
        int run = 0;
        for (int i2 = 0; i2 < 16; ++i2) { int tv = wsum[i2]; wsum[i2] = run; run += tv; }
    }
    __syncthreads();
    ss[tid + 1] = v + wsum[w];
    if (tid == 0) ss[0] = 0;
    __syncthreads();

    // ---- map compact sorted position -> (cell, slot) via binary search ----
    const int spos = qbase + lane;
    int lo = 0;
    #pragma unroll
    for (int stp = 512; stp >= 1; stp >>= 1) {
        int nlo = lo + stp;
        if (ss[nlo] <= spos) lo = nlo;
    }
    const int qc = lo;
    float4 Q = rs4[qc * CAP + (spos - ss[qc])];
    const float qx = Q.x, qy = Q.y, qz = Q.z;
    const int cx = clampg((int)(qx * (float)G));
    const int cy = clampg((int)(qy * (float)G));
    const int cz = clampg((int)(qz * (float)G));

    unsigned bq[KNN];
    #pragma unroll
    for (int k = 0; k < KNN; ++k) bq[k] = 0xFFFFFFFFu;

    auto scanRange = [&](int base, int s0, int s1, unsigned cutv) {
        for (int t2 = s0; t2 < s1; ++t2) {
            float4 P = rs4[base + t2];
            float dx = qx - P.x, dy = qy - P.y, dz = qz - P.z;
            float d = fmaf(dx, dx, fmaf(dy, dy, dz * dz));
            unsigned vk = (__float_as_uint(d) & TRUNCM) | __float_as_uint(P.w);
            unsigned cv = cutv < bq[15] ? cutv : bq[15];
            if (vk < cv) {
                bq[15] = vk;
                #pragma unroll
                for (int kk = 15; kk >= 1; --kk) {
                    unsigned l2 = min(bq[kk - 1], bq[kk]);
                    unsigned h2 = max(bq[kk - 1], bq[kk]);
                    bq[kk - 1] = l2; bq[kk] = h2;
                }
            }
        }
    };

    auto mergeToW0 = [&]() {
        #pragma unroll
        for (int rnd = 0; rnd < 4; ++rnd) {
            int s = 1 << rnd;
            int slot = w >> (rnd + 1);
            __syncthreads();
            if ((w & (2 * s - 1)) == s) {
                #pragma unroll
                for (int k = 0; k < KNN; ++k) sld[slot][lane][k] = bq[k];
            }
            __syncthreads();
            if ((w & (2 * s - 1)) == 0) {
                #pragma unroll
                for (int k = 0; k < KNN; ++k) {
                    unsigned vk = sld[slot][lane][k];
                    if (vk < bq[15]) {
                        bq[15] = vk;
                        #pragma unroll
                        for (int kk = 15; kk >= 1; --kk) {
                            unsigned l2 = min(bq[kk - 1], bq[kk]);
                            unsigned h2 = max(bq[kk - 1], bq[kk]);
                            bq[kk - 1] = l2; bq[kk] = h2;
                        }
                    }
                }
            }
        }
    };

    // ---- initial 27-cell box, 54 half-cell chunks over 16 waves ----
    {
        int counter = 0;
        #pragma unroll
        for (int dz = -1; dz <= 1; ++dz)
        #pragma unroll
        for (int dy = -1; dy <= 1; ++dy)
        #pragma unroll
        for (int dx = -1; dx <= 1; ++dx) {
            #pragma unroll
            for (int h = 0; h < 2; ++h) {
                int cc = counter++;
                if ((cc & 15) != w) continue;
                int nx = cx + dx, ny = cy + dy, nz = cz + dz;
                if ((unsigned)nx > (unsigned)(G - 1) || (unsigned)ny > (unsigned)(G - 1) ||
                    (unsigned)nz > (unsigned)(G - 1)) continue;
                int cell = (nz * G + ny) * G + nx;
                int cnt = scnt[cell];
                int mid = cnt >> 1;
                if (h == 0) scanRange(cell * CAP, 0, mid, 0xFFFFFFFFu);
                else        scanRange(cell * CAP, mid, cnt, 0xFFFFFFFFu);
            }
        }
    }
    mergeToW0();

    // ---- expanding shells with exact box-margin certificate ----
    int r_done = 1;
    while (true) {
        if (tid == 0) flagS = 0;
        __syncthreads();
        if (w == 0) {
            float mx = FLTMAX;
            if (cx - r_done > 0)     mx = fminf(mx, qx - (float)(cx - r_done) * CELLSZ);
            if (cx + r_done < G - 1) mx = fminf(mx, (float)(cx + r_done + 1) * CELLSZ - qx);
            if (cy - r_done > 0)     mx = fminf(mx, qy - (float)(cy - r_done) * CELLSZ);
            if (cy + r_done < G - 1) mx = fminf(mx, (float)(cy + r_done + 1) * CELLSZ - qy);
            if (cz - r_done > 0)     mx = fminf(mx, qz - (float)(cz - r_done) * CELLSZ);
            if (cz + r_done < G - 1) mx = fminf(mx, (float)(cz + r_done + 1) * CELLSZ - qz);
            float d16t = __uint_as_float(bq[15] & TRUNCM);
            bool dn = d16t <= mx * mx * 0.998f;
            cutp[lane]  = bq[15];
            doneA[lane] = dn ? 1 : 0;
            bool anyn = __any(!dn);
            if (anyn && lane == 0) flagS = 1;
        }
        __syncthreads();
        if (!flagS || r_done >= G) break;
        int r = r_done + 1;
        if (w != 0) {
            #pragma unroll
            for (int k = 0; k < KNN; ++k) bq[k] = 0xFFFFFFFFu;
        }
        unsigned cut = cutp[lane];
        float cutub = __uint_as_float(cut | IDXM);   // tie-safe upper bound on d^2
        bool active = !doneA[lane];
        int counter = 0;
        for (int dz = -r; dz <= r; ++dz)
        for (int dy = -r; dy <= r; ++dy)
        for (int dx = -r; dx <= r; ++dx) {
            int adx = dx < 0 ? -dx : dx, ady = dy < 0 ? -dy : dy, adz = dz < 0 ? -dz : dz;
            int m = adx > ady ? adx : ady; m = m > adz ? m : adz;
            if (m != r) continue;
            int cc = counter++;
            if ((cc & 15) != w) continue;
            if (!active) continue;
            int nx = cx + dx, ny = cy + dy, nz = cz + dz;
            if ((unsigned)nx > (unsigned)(G - 1) || (unsigned)ny > (unsigned)(G - 1) ||
                (unsigned)nz > (unsigned)(G - 1)) continue;
            // per-cell min-d^2 prune
            float ex0 = (float)nx * CELLSZ;
            float ey0 = (float)ny * CELLSZ;
            float ez0 = (float)nz * CELLSZ;
            float ddx = fmaxf(0.f, fmaxf(ex0 - qx, qx - ex0 - CELLSZ));
            float ddy = fmaxf(0.f, fmaxf(ey0 - qy, qy - ey0 - CELLSZ));
            float ddz = fmaxf(0.f, fmaxf(ez0 - qz, qz - ez0 - CELLSZ));
            float d2min = fmaf(ddx, ddx, fmaf(ddy, ddy, ddz * ddz));
            if (d2min > cutub) continue;
            int cell = (nz * G + ny) * G + nx;
            scanRange(cell * CAP, 0, scnt[cell], cut);
        }
        mergeToW0();
        r_done = r;
    }

    if (w != 0) return;

    // ---- epilogue: gather by original index + mask + Gram + cond ----
    const float* refb = ref + (size_t)b * NPTS * 3;
    const float* ptsb = pts + (size_t)b * NPTS * 3;
    float rx[KNN], ry[KNN], rz[KNN], px[KNN], py[KNN], pz[KNN];
    int mbits = 0;
    float sRx = 0.f, sRy = 0.f, sRz = 0.f, sPx = 0.f, sPy = 0.f, sPz = 0.f;
    #pragma unroll
    for (int k = 0; k < KNN; ++k) {
        int i = (int)(bq[k] & IDXM);
        float du = __uint_as_float(bq[k] & TRUNCM);
        rx[k] = refb[3 * i]; ry[k] = refb[3 * i + 1]; rz[k] = refb[3 * i + 2];
        px[k] = ptsb[3 * i]; py[k] = ptsb[3 * i + 1]; pz[k] = ptsb[3 * i + 2];
        if (du < BALL2f) {
            mbits |= (1 << k);
            sRx += rx[k]; sRy += ry[k]; sRz += rz[k];
        }
        sPx += px[k]; sPy += py[k]; sPz += pz[k];
    }
    int nb = __popc(mbits);
    double inb = 1.0 / (double)nb;
    double cRx = (double)sRx * inb, cRy = (double)sRy * inb, cRz = (double)sRz * inb;
    double cPx = (double)sPx * inb, cPy = (double)sPy * inb, cPz = (double)sPz * inb;

    double Rxx = 0, Rxy = 0, Rxz = 0, Ryy = 0, Ryz = 0, Rzz = 0;
    double Pxx = 0, Pxy = 0, Pxz = 0, Pyy = 0, Pyz = 0, Pzz = 0;
    #pragma unroll
    for (int k = 0; k < KNN; ++k) {
        bool m = (mbits >> k) & 1;
        double ax = (m ? (double)rx[k] : 0.0) - cRx;
        double ay = (m ? (double)ry[k] : 0.0) - cRy;
        double az = (m ? (double)rz[k] : 0.0) - cRz;
        Rxx += ax * ax; Rxy += ax * ay; Rxz += ax * az;
        Ryy += ay * ay; Ryz += ay * az; Rzz += az * az;
        double bx = (double)px[k] - cPx;
        double by = (double)py[k] - cPy;
        double bz = (double)pz[k] - cPz;
        Pxx += bx * bx; Pxy += bx * by; Pxz += bx * bz;
        Pyy += by * by; Pyz += by * bz; Pzz += bz * bz;
    }
    double condR = cond3(Rxx, Rxy, Rxz, Ryy, Ryz, Rzz);
    double condP = cond3(Pxx, Pxy, Pxz, Pyy, Pyz, Pzz);
    double t = condP - condR;
    t = t * t;

    #pragma unroll
    for (int off = 32; off > 0; off >>= 1) t += __shfl_down(t, off);
    if (lane == 0) {
        atomicAdd(acc, t);
        __threadfence();
        int prev = atomicAdd(done, 1);
        if (prev == NBLK - 1) {
            __threadfence();
            double total = atomicAdd(acc, 0.0);     // coherent RMW read
            out[0] = (float)(total * (1.0 / 16384.0));
        }
    }
}

extern "C" void kernel_launch(void* const* d_in, const int* in_sizes, int n_in,
                              void* d_out, int out_size, void* d_ws, size_t ws_size,
                              hipStream_t stream) {
    const float* ref = (const float*)d_in[0];
    const float* pts = (const float*)d_in[1];
    char* ws = (char*)d_ws;
    double* acc   = (double*)(ws + WS_ACC);
    int* done     = (int*)(ws + WS_DONE);
    int* gcnt     = (int*)(ws + WS_CNT);
    float4* rsort = (float4*)(ws + WS_RSORT);

    hipMemsetAsync(ws, 0, WS_ZERO, stream);
    hipLaunchKernelGGL(bin_kernel,      dim3(64),   dim3(256),  0, stream, ref, gcnt, rsort);
    hipLaunchKernelGGL(cond_knn_kernel, dim3(NBLK), dim3(1024), 0, stream,
                       ref, pts, rsort, gcnt, acc, done, (float*)d_out);
}